// Round 4
// baseline (1215.661 us; speedup 1.0000x reference)
//
#include <hip/hip_runtime.h>
#include <float.h>

#define B_  32
#define C_  3
#define H_  64
#define W_  64
#define N_  2048
#define D_  128
#define KNN 8
#define PS  75     // 3*5*5
#define NCHUNK 1024  // dictionary patches per wave (2-way split)

// ---------------------------------------------------------------------------
// Kernel 1: bias[n] = 0.5 * ||patches[n]||^2
// ---------------------------------------------------------------------------
__global__ __launch_bounds__(256) void bias_kernel(const float* __restrict__ patches,
                                                   float* __restrict__ bias) {
  int n = blockIdx.x * 256 + threadIdx.x;
  if (n < N_) {
    const float* __restrict__ p = patches + n * PS;
    float s = 0.f;
#pragma unroll
    for (int j = 0; j < PS; j++) s += p[j] * p[j];
    bias[n] = 0.5f * s;
  }
}

// streaming top-8 insert, fully unrolled, register-resident arrays
__device__ __forceinline__ void insert8(float d, int idx, float td[KNN], int ti[KNN],
                                        float& tmax, int& tslot) {
  if (d < tmax) {
#pragma unroll
    for (int s = 0; s < KNN; s++) if (s == tslot) { td[s] = d; ti[s] = idx; }
    float m = td[0]; int ms = 0;
#pragma unroll
    for (int s = 1; s < KNN; s++) if (td[s] > m) { m = td[s]; ms = s; }
    tmax = m; tslot = ms;
  }
}

// ---------------------------------------------------------------------------
// Kernel 2: block = 256 threads = 4 waves = 2 pixel-groups x 2 dictionary
// chunks. Each wave scans 1024 patches for its 64 pixels (wave-uniform patch
// base -> scalar-pipe loads). Chunk-1 waves ship their top-8 through LDS;
// chunk-0 waves merge and run the epilogue.
//
// Restructured vs previous session: 4 patches per iteration, ONE accumulator
// chain per patch (4 independent chains cover the ~4-cycle v_fmac latency),
// and xv[j] reused across all 4 streams so the allocator keeps the 75-float
// x-patch register-resident (previous build: VGPR=52 < 75 -> xv was not in
// registers; VALU-issue time was 2.66x the FMA floor).
// amdgpu_waves_per_eu(3,4) kept from the verified build: allows up to ~170
// VGPRs; at the expected ~110 VGPRs the runtime still fits the grid's
// 4 waves/EU.
// ---------------------------------------------------------------------------
__global__ __launch_bounds__(256)
__attribute__((amdgpu_waves_per_eu(3, 4)))
void topk_kernel(const float* __restrict__ x, const float* __restrict__ patches,
                 const float* __restrict__ values, const float* __restrict__ bias,
                 float* __restrict__ out) {
  const int lane = threadIdx.x & 63;
  const int wid = threadIdx.x >> 6;
  const int chunk = __builtin_amdgcn_readfirstlane(wid & 1);  // force uniform
  const int pgrp = wid >> 1;
  const int pix = blockIdx.x * 128 + pgrp * 64 + lane;
  const int w = pix & 63;
  const int h = (pix >> 6) & 63;
  const int b = pix >> 12;

  // ---- x-patch (75 floats) into registers, zero-padded (PAD=2) ----
  float xv[PS];
#pragma unroll
  for (int c = 0; c < C_; c++) {
#pragma unroll
    for (int dh = 0; dh < 5; dh++) {
      const int hh = h + dh - 2;
#pragma unroll
      for (int dw = 0; dw < 5; dw++) {
        const int ww = w + dw - 2;
        const bool ok = ((unsigned)hh < 64u) && ((unsigned)ww < 64u);
        xv[(c * 5 + dh) * 5 + dw] = ok ? x[((b * C_ + c) * H_ + hh) * W_ + ww] : 0.f;
      }
    }
  }

  float td[KNN];
  int ti[KNN];
#pragma unroll
  for (int s = 0; s < KNN; s++) { td[s] = FLT_MAX; ti[s] = 0; }
  float tmax = FLT_MAX;
  int tslot = 0;

  // ---- main scan: 4 patches / iter, 1 accumulator chain per patch ----
  const int n0 = chunk * NCHUNK;
#pragma unroll 1
  for (int i = 0; i < NCHUNK; i += 4) {
    const int n = n0 + i;
    const float* __restrict__ p = patches + n * PS;  // wave-uniform base
    float d0 = 0.f, d1 = 0.f, d2 = 0.f, d3 = 0.f;
#pragma unroll
    for (int j = 0; j < PS; j++) {
      const float xj = xv[j];
      d0 = fmaf(p[j],          xj, d0);
      d1 = fmaf(p[PS + j],     xj, d1);
      d2 = fmaf(p[2 * PS + j], xj, d2);
      d3 = fmaf(p[3 * PS + j], xj, d3);
    }
    insert8(bias[n]     - d0, n,     td, ti, tmax, tslot);
    insert8(bias[n + 1] - d1, n + 1, td, ti, tmax, tslot);
    insert8(bias[n + 2] - d2, n + 2, td, ti, tmax, tslot);
    insert8(bias[n + 3] - d3, n + 3, td, ti, tmax, tslot);
  }

  // ---- cross-wave merge through LDS ----
  __shared__ float lds_d[2][64][KNN];
  __shared__ int lds_i[2][64][KNN];
  if (chunk == 1) {
#pragma unroll
    for (int s = 0; s < KNN; s++) {
      lds_d[pgrp][lane][s] = td[s];
      lds_i[pgrp][lane][s] = ti[s];
    }
  }
  __syncthreads();
  if (chunk == 0) {
#pragma unroll
    for (int s = 0; s < KNN; s++)
      insert8(lds_d[pgrp][lane][s], lds_i[pgrp][lane][s], td, ti, tmax, tslot);

    // ---- gather + mean + store (lanes = consecutive w -> coalesced) ----
    int base[KNN];
#pragma unroll
    for (int s = 0; s < KNN; s++) base[s] = ti[s] * D_;
    const int obase = b * (D_ * H_ * W_) + h * W_ + w;
#pragma unroll 1
    for (int dd = 0; dd < D_; dd += 4) {
      float s0 = 0.f, s1 = 0.f, s2 = 0.f, s3 = 0.f;
#pragma unroll
      for (int k = 0; k < KNN; k++) {
        const float4 v = *(const float4*)(values + base[k] + dd);
        s0 += v.x; s1 += v.y; s2 += v.z; s3 += v.w;
      }
      out[obase + (dd + 0) * (H_ * W_)] = s0 * 0.125f;
      out[obase + (dd + 1) * (H_ * W_)] = s1 * 0.125f;
      out[obase + (dd + 2) * (H_ * W_)] = s2 * 0.125f;
      out[obase + (dd + 3) * (H_ * W_)] = s3 * 0.125f;
    }
  }
}

// ---------------------------------------------------------------------------
extern "C" void kernel_launch(void* const* d_in, const int* in_sizes, int n_in,
                              void* d_out, int out_size, void* d_ws, size_t ws_size,
                              hipStream_t stream) {
  const float* x = (const float*)d_in[0];
  const float* patches = (const float*)d_in[1];
  const float* values = (const float*)d_in[2];
  float* out = (float*)d_out;
  float* bias = (float*)d_ws;  // 2048 floats of scratch

  hipLaunchKernelGGL(bias_kernel, dim3(N_ / 256), dim3(256), 0, stream, patches, bias);
  hipLaunchKernelGGL(topk_kernel, dim3((B_ * H_ * W_) / 128), dim3(256), 0, stream,
                     x, patches, values, bias, out);
}

// Round 7
// 726.985 us; speedup vs baseline: 1.6722x; 1.6722x over previous
//
#include <hip/hip_runtime.h>
#include <float.h>

#define B_  32
#define C_  3
#define H_  64
#define W_  64
#define N_  2048
#define D_  128
#define KNN 8
#define PS  75       // 3*5*5
#define TILES 128    // N_/16 patch tiles
#define CK  12       // coarse per-lane top-k (margin over 8 for f16 ranking noise)

typedef __attribute__((ext_vector_type(8))) _Float16 kh8;   // register-only (MFMA A/B)
typedef __attribute__((ext_vector_type(4))) float kvf4;     // register-only (MFMA C/D)

// ---------------------------------------------------------------------------
// Kernel 1: nbias[n] = -0.5 * ||patches[n]||^2  (negated: C-init for the MFMA,
// D = <p,x> - 0.5||p||^2 = -dist, no negation needed on A)
// ---------------------------------------------------------------------------
__global__ __launch_bounds__(256) void bias_kernel(const float* __restrict__ patches,
                                                   float* __restrict__ nbias) {
  int n = blockIdx.x * 256 + threadIdx.x;
  if (n < N_) {
    const float* __restrict__ p = patches + n * PS;
    float s = 0.f;
#pragma unroll
    for (int j = 0; j < PS; j++) s += p[j] * p[j];
    nbias[n] = -0.5f * s;
  }
}

// branchless ascending bubble insert into a CK-deep sorted register list
__device__ __forceinline__ void bub12(unsigned (&s)[CK], unsigned c) {
#pragma unroll
  for (int j = 0; j < CK; j++) {
    const unsigned lo = s[j] < c ? s[j] : c;
    const unsigned hi = s[j] < c ? c : s[j];
    s[j] = lo;
    c = hi;
  }
}

// lexicographic (d, idx) ascending 8-deep bubble insert
__device__ __forceinline__ void ins8(float cd, int ci, float (&rd)[KNN], int (&ri)[KNN]) {
#pragma unroll
  for (int q = 0; q < KNN; q++) {
    const bool sw = (cd < rd[q]) || (cd == rd[q] && ci < ri[q]);
    const float nd = sw ? rd[q] : cd;
    const int   ni = sw ? ri[q] : ci;
    rd[q] = sw ? cd : rd[q];
    ri[q] = sw ? ci : ri[q];
    cd = nd;
    ci = ni;
  }
}

// ---------------------------------------------------------------------------
// Kernel 2: block = 256 threads = 4 waves; wave `wid` owns pixel row h0+wid
// (64 pixels = 4 MFMA column-groups of 16). Coarse distances via
// mfma_f32_16x16x32_f16 against all 2048 patches; lane (l15,g4) keeps a
// branchless top-CK of packed keys (dist[31:11] | idx[10:0]) over its
// {n : n mod 16 in [g4*4, g4*4+4)} slice. Exact fp32 rescore of each lane's
// CK candidates -> per-lane lex top-8 -> LDS merge across the 4 g4 lanes
// (baseline-proven pattern, NO cross-lane shuffles) -> 4 lanes split D=128
// for the gather/mean. No ext-vector global loads anywhere (scalar nbias,
// float4 values like the verified baseline). Gather indices masked to
// [0,2047] as fault-defense.
// ---------------------------------------------------------------------------
__global__ __launch_bounds__(256)
__attribute__((amdgpu_waves_per_eu(2, 4)))
void knn_kernel(const float* __restrict__ x, const float* __restrict__ patches,
                const float* __restrict__ values, const float* __restrict__ nbias,
                float* __restrict__ out) {
  __shared__ float xt[1633];                 // [3][8][68] zero-padded x tile + zero cell
  __shared__ float mg_d[4][4][16][KNN];      // [wid][g4][l15][slot] merge staging
  __shared__ int   mg_i[4][4][16][KNN];
  __shared__ int   bc_i[4][16][KNN];         // merged idx broadcast [wid][l15][slot]

  const int tid = threadIdx.x;
  const int bp = blockIdx.x * 256;           // first pixel of this block
  const int b  = bp >> 12;
  const int h0 = (bp >> 6) & 63;             // multiple of 4

  for (int f = tid; f < 1632; f += 256) {
    const int c   = f / 544;
    const int rem = f - c * 544;
    const int j   = rem / 68;
    const int col = rem - j * 68;
    const int gr = h0 - 2 + j;
    const int gc = col - 2;
    float v = 0.f;
    if ((unsigned)gr < 64u && (unsigned)gc < 64u)
      v = x[((b * 3 + c) * 64 + gr) * 64 + gc];
    xt[f] = v;
  }
  if (tid == 0) xt[1632] = 0.f;
  __syncthreads();

  const int lane = tid & 63;
  const int wid  = tid >> 6;                 // pixel row = h0 + wid
  const int l15  = lane & 15;
  const int g4   = lane >> 4;

  // ---- B fragments (f16 x-windows); snorm via direct LDS reads (no shuffle) ----
  kh8 bfr[4][3];
  float snorm[4];
#pragma unroll
  for (int g = 0; g < 4; g++) {
    const int pb = wid * 68 + g * 16 + l15;
#pragma unroll
    for (int s = 0; s < 3; s++) {
      union { _Float16 h[8]; kh8 v; } fr;
#pragma unroll
      for (int i = 0; i < 8; i++) {
        const int k  = s * 32 + g4 * 8 + i;
        const int c  = k / 25;
        const int r2 = k - c * 25;
        const int addr = (k < PS) ? (pb + c * 544 + (r2 / 5) * 68 + (r2 % 5)) : 1632;
        fr.h[i] = (_Float16)xt[addr];
      }
      bfr[g][s] = fr.v;
    }
    float sq = 0.f;
#pragma unroll
    for (int c = 0; c < 3; c++)
#pragma unroll
      for (int dh = 0; dh < 5; dh++)
#pragma unroll
        for (int dw = 0; dw < 5; dw++) {
          const _Float16 hv = (_Float16)xt[pb + c * 544 + dh * 68 + dw];
          const float vr = (float)hv;
          sq = fmaf(vr, vr, sq);
        }
    snorm[g] = 0.5f * sq;
  }

  // ---- coarse top-CK per lane ----
  unsigned sk0[CK], sk1[CK], sk2[CK], sk3[CK];
#pragma unroll
  for (int j = 0; j < CK; j++) sk0[j] = sk1[j] = sk2[j] = sk3[j] = 0xFFFFFFFFu;

#pragma unroll 1
  for (int t = 0; t < TILES; t++) {
    // A-fragment: patch row m = t*16 + l15, k-slice base g4*8 (+32 per step)
    const float* __restrict__ pr = patches + (t * 16 + l15) * PS + g4 * 8;
    union { _Float16 h[8]; kh8 v; } af[3];
#pragma unroll
    for (int s = 0; s < 3; s++)
#pragma unroll
      for (int i = 0; i < 8; i++) {
        const int k = s * 32 + g4 * 8 + i;
        const float e = (k < PS) ? pr[s * 32 + i] : 0.f;   // masked, no OOB
        af[s].h[i] = (_Float16)e;
      }

    const int nbb = t * 16 + g4 * 4;
    const float nb0 = nbias[nbb + 0];        // scalar loads (no vector-cast)
    const float nb1 = nbias[nbb + 1];
    const float nb2 = nbias[nbb + 2];
    const float nb3 = nbias[nbb + 3];
    const unsigned tb = (unsigned)nbb;
#pragma unroll
    for (int g = 0; g < 4; g++) {
      kvf4 acc;
      acc[0] = nb0; acc[1] = nb1; acc[2] = nb2; acc[3] = nb3;
      acc = __builtin_amdgcn_mfma_f32_16x16x32_f16(af[0].v, bfr[g][0], acc, 0, 0, 0);
      acc = __builtin_amdgcn_mfma_f32_16x16x32_f16(af[1].v, bfr[g][1], acc, 0, 0, 0);
      acc = __builtin_amdgcn_mfma_f32_16x16x32_f16(af[2].v, bfr[g][2], acc, 0, 0, 0);
#pragma unroll
      for (int r = 0; r < 4; r++) {
        float kv = snorm[g] - acc[r];        // = 0.5||p-x||^2 >= 0 (up to rounding)
        kv = fmaxf(kv, 0.f);                 // keep uint order == float order
        const unsigned ku = (__float_as_uint(kv) & 0xFFFFF800u) | (tb + (unsigned)r);
        if      (g == 0) bub12(sk0, ku);
        else if (g == 1) bub12(sk1, ku);
        else if (g == 2) bub12(sk2, ku);
        else             bub12(sk3, ku);
      }
    }
  }

  // ---- per-g: fp32 rescore -> per-lane top-8 -> LDS merge -> gather/store ----
#pragma unroll 1
  for (int g = 0; g < 4; g++) {
    float xv[PS];
    const int pb = wid * 68 + g * 16 + l15;
#pragma unroll
    for (int c = 0; c < 3; c++)
#pragma unroll
      for (int dh = 0; dh < 5; dh++)
#pragma unroll
        for (int dw = 0; dw < 5; dw++)
          xv[(c * 5 + dh) * 5 + dw] = xt[pb + c * 544 + dh * 68 + dw];

    float rd[KNN];
    int ri[KNN];
#pragma unroll
    for (int j = 0; j < KNN; j++) { rd[j] = FLT_MAX; ri[j] = 0; }

#pragma unroll 1
    for (int j = 0; j < CK; j++) {
      const unsigned cj = (g == 0) ? sk0[j] : (g == 1) ? sk1[j] : (g == 2) ? sk2[j] : sk3[j];
      const int idx = (int)(cj & 0x7FFu);
      const float* __restrict__ pp = patches + idx * PS;
      float d0 = 0.f, d1 = 0.f, d2 = 0.f, d3 = 0.f;
#pragma unroll
      for (int u = 0; u < 18; u++) {
        d0 = fmaf(pp[4 * u + 0], xv[4 * u + 0], d0);
        d1 = fmaf(pp[4 * u + 1], xv[4 * u + 1], d1);
        d2 = fmaf(pp[4 * u + 2], xv[4 * u + 2], d2);
        d3 = fmaf(pp[4 * u + 3], xv[4 * u + 3], d3);
      }
      d0 = fmaf(pp[72], xv[72], d0);
      d1 = fmaf(pp[73], xv[73], d1);
      d2 = fmaf(pp[74], xv[74], d2);
      const float dot = (d0 + d1) + (d2 + d3);
      const float cd = -(nbias[idx] + dot);  // = 0.5||p||^2 - <p,x>, exact fp32
      ins8(cd, idx, rd, ri);
    }

    // dump per-lane top-8 to LDS; lane g4==0 merges the 4 disjoint subsets
#pragma unroll
    for (int s = 0; s < KNN; s++) {
      mg_d[wid][g4][l15][s] = rd[s];
      mg_i[wid][g4][l15][s] = ri[s];
    }
    __syncthreads();
    if (g4 == 0) {
#pragma unroll
      for (int q = 1; q < 4; q++)
#pragma unroll
        for (int s = 0; s < KNN; s++)
          ins8(mg_d[wid][q][l15][s], mg_i[wid][q][l15][s], rd, ri);
#pragma unroll
      for (int s = 0; s < KNN; s++) bc_i[wid][l15][s] = ri[s];
    }
    __syncthreads();

    // all 4 lanes read merged indices; lane handles dims [g4*32, g4*32+32)
    int mi[KNN];
#pragma unroll
    for (int s = 0; s < KNN; s++) mi[s] = bc_i[wid][l15][s] & 0x7FF;  // fault-defense
    const int obase = ((b * D_ + g4 * 32) * 64 + (h0 + wid)) * 64 + (g * 16 + l15);
#pragma unroll 1
    for (int dd = 0; dd < 32; dd += 4) {
      float s0 = 0.f, s1 = 0.f, s2 = 0.f, s3 = 0.f;
#pragma unroll
      for (int k = 0; k < KNN; k++) {
        const float4 v = *(const float4*)(values + mi[k] * D_ + g4 * 32 + dd);
        s0 += v.x; s1 += v.y; s2 += v.z; s3 += v.w;
      }
      out[obase + (dd + 0) * 4096] = s0 * 0.125f;
      out[obase + (dd + 1) * 4096] = s1 * 0.125f;
      out[obase + (dd + 2) * 4096] = s2 * 0.125f;
      out[obase + (dd + 3) * 4096] = s3 * 0.125f;
    }
  }
}

// ---------------------------------------------------------------------------
extern "C" void kernel_launch(void* const* d_in, const int* in_sizes, int n_in,
                              void* d_out, int out_size, void* d_ws, size_t ws_size,
                              hipStream_t stream) {
  const float* x = (const float*)d_in[0];
  const float* patches = (const float*)d_in[1];
  const float* values = (const float*)d_in[2];
  float* out = (float*)d_out;
  float* nbias = (float*)d_ws;  // 2048 floats of scratch (8 KB)

  hipLaunchKernelGGL(bias_kernel, dim3(N_ / 256), dim3(256), 0, stream, patches, nbias);
  hipLaunchKernelGGL(knn_kernel, dim3((B_ * H_ * W_) / 256), dim3(256), 0, stream,
                     x, patches, values, nbias, out);
}

// Round 8
// 643.865 us; speedup vs baseline: 1.8881x; 1.1291x over previous
//
#include <hip/hip_runtime.h>
#include <float.h>

#define B_  32
#define C_  3
#define H_  64
#define W_  64
#define N_  2048
#define D_  128
#define KNN 8
#define PS  75       // 3*5*5
#define TILES 128    // N_/16 patch tiles
#define CK  12       // coarse per-lane top-k (margin over 8 for f16 ranking noise)

typedef __attribute__((ext_vector_type(8))) _Float16 kh8;   // register-only (MFMA A/B)
typedef __attribute__((ext_vector_type(4))) float kvf4;     // register-only (MFMA C/D)

struct FragPOD { unsigned a, b, c, d; };   // 16B POD for global frag store/load

// ---------------------------------------------------------------------------
// Kernel 1: nbias[n] = -0.5 * ||patches[n]||^2  (negated: C-init for the MFMA,
// D = <p,x> - 0.5||p||^2 = -dist, no negation needed on A)
// ---------------------------------------------------------------------------
__global__ __launch_bounds__(256) void bias_kernel(const float* __restrict__ patches,
                                                   float* __restrict__ nbias) {
  int n = blockIdx.x * 256 + threadIdx.x;
  if (n < N_) {
    const float* __restrict__ p = patches + n * PS;
    float s = 0.f;
#pragma unroll
    for (int j = 0; j < PS; j++) s += p[j] * p[j];
    nbias[n] = -0.5f * s;
  }
}

// ---------------------------------------------------------------------------
// Kernel 1b: A-fragments (f16, MFMA layout) precomputed once. Tile t, K-step s,
// lane l: elem i <-> (m = t*16+(l&15), k = s*32+(l>>4)*8+i), masked k<75.
// Same content as the (passing) R7 in-kernel build -> bit-identical distances.
// ---------------------------------------------------------------------------
__global__ __launch_bounds__(192) void pfrag_kernel(const float* __restrict__ patches,
                                                    FragPOD* __restrict__ pfrag) {
  const int t = blockIdx.x;
  const int s = threadIdx.x >> 6;
  const int l = threadIdx.x & 63;
  const int m = t * 16 + (l & 15);
  const int g4 = l >> 4;
  union { _Float16 h[8]; FragPOD f; } fr;
#pragma unroll
  for (int i = 0; i < 8; i++) {
    const int k = s * 32 + g4 * 8 + i;
    const float v = (k < PS) ? patches[m * PS + k] : 0.f;
    fr.h[i] = (_Float16)v;
  }
  pfrag[(t * 3 + s) * 64 + l] = fr.f;
}

// branchless ascending bubble insert into a CK-deep sorted register list
__device__ __forceinline__ void bub12(unsigned (&s)[CK], unsigned c) {
#pragma unroll
  for (int j = 0; j < CK; j++) {
    const unsigned lo = s[j] < c ? s[j] : c;
    const unsigned hi = s[j] < c ? c : s[j];
    s[j] = lo;
    c = hi;
  }
}

// lexicographic (d, idx) ascending 8-deep bubble insert
__device__ __forceinline__ void ins8(float cd, int ci, float (&rd)[KNN], int (&ri)[KNN]) {
#pragma unroll
  for (int q = 0; q < KNN; q++) {
    const bool sw = (cd < rd[q]) || (cd == rd[q] && ci < ri[q]);
    const float nd = sw ? rd[q] : cd;
    const int   ni = sw ? ri[q] : ci;
    rd[q] = sw ? cd : rd[q];
    ri[q] = sw ? ci : ri[q];
    cd = nd;
    ci = ni;
  }
}

// ---------------------------------------------------------------------------
// Kernel 2 (structure = round-7 PASSING kernel; A-build swapped for coalesced
// precomputed-fragment loads + 1-tile software prefetch to kill the per-tile
// scalar-load latency and the scratch spills R7's counters showed).
// ---------------------------------------------------------------------------
__global__ __launch_bounds__(256)
__attribute__((amdgpu_waves_per_eu(2, 4)))
void knn_kernel(const float* __restrict__ x, const float* __restrict__ patches,
                const float* __restrict__ values, const float* __restrict__ nbias,
                const FragPOD* __restrict__ pfrag, float* __restrict__ out) {
  __shared__ float xt[1633];                 // [3][8][68] zero-padded x tile + zero cell
  __shared__ float mg_d[4][4][16][KNN];      // [wid][g4][l15][slot] merge staging
  __shared__ int   mg_i[4][4][16][KNN];
  __shared__ int   bc_i[4][16][KNN];         // merged idx broadcast [wid][l15][slot]

  const int tid = threadIdx.x;
  const int bp = blockIdx.x * 256;           // first pixel of this block
  const int b  = bp >> 12;
  const int h0 = (bp >> 6) & 63;             // multiple of 4

  for (int f = tid; f < 1632; f += 256) {
    const int c   = f / 544;
    const int rem = f - c * 544;
    const int j   = rem / 68;
    const int col = rem - j * 68;
    const int gr = h0 - 2 + j;
    const int gc = col - 2;
    float v = 0.f;
    if ((unsigned)gr < 64u && (unsigned)gc < 64u)
      v = x[((b * 3 + c) * 64 + gr) * 64 + gc];
    xt[f] = v;
  }
  if (tid == 0) xt[1632] = 0.f;
  __syncthreads();

  const int lane = tid & 63;
  const int wid  = tid >> 6;                 // pixel row = h0 + wid
  const int l15  = lane & 15;
  const int g4   = lane >> 4;

  // ---- B fragments (f16 x-windows); snorm via direct LDS reads (no shuffle) ----
  kh8 bfr[4][3];
  float snorm[4];
#pragma unroll
  for (int g = 0; g < 4; g++) {
    const int pb = wid * 68 + g * 16 + l15;
#pragma unroll
    for (int s = 0; s < 3; s++) {
      union { _Float16 h[8]; kh8 v; } fr;
#pragma unroll
      for (int i = 0; i < 8; i++) {
        const int k  = s * 32 + g4 * 8 + i;
        const int c  = k / 25;
        const int r2 = k - c * 25;
        const int addr = (k < PS) ? (pb + c * 544 + (r2 / 5) * 68 + (r2 % 5)) : 1632;
        fr.h[i] = (_Float16)xt[addr];
      }
      bfr[g][s] = fr.v;
    }
    float sq = 0.f;
#pragma unroll
    for (int c = 0; c < 3; c++)
#pragma unroll
      for (int dh = 0; dh < 5; dh++)
#pragma unroll
        for (int dw = 0; dw < 5; dw++) {
          const _Float16 hv = (_Float16)xt[pb + c * 544 + dh * 68 + dw];
          const float vr = (float)hv;
          sq = fmaf(vr, vr, sq);
        }
    snorm[g] = 0.5f * sq;
  }

  // ---- coarse top-CK per lane ----
  unsigned sk0[CK], sk1[CK], sk2[CK], sk3[CK];
#pragma unroll
  for (int j = 0; j < CK; j++) sk0[j] = sk1[j] = sk2[j] = sk3[j] = 0xFFFFFFFFu;

  const unsigned ib = (unsigned)(g4 * 4);

  // prefetch tile 0
  FragPOD c0 = pfrag[lane];
  FragPOD c1 = pfrag[64 + lane];
  FragPOD c2 = pfrag[128 + lane];
  float nb0 = nbias[g4 * 4 + 0];
  float nb1 = nbias[g4 * 4 + 1];
  float nb2 = nbias[g4 * 4 + 2];
  float nb3 = nbias[g4 * 4 + 3];

#pragma unroll 1
  for (int t = 0; t < TILES; t++) {
    union { FragPOD f; kh8 v; } a0, a1, a2;
    a0.f = c0; a1.f = c1; a2.f = c2;
    const float b0 = nb0, b1 = nb1, b2 = nb2, b3 = nb3;

    // prefetch tile t+1 (t=127 wraps to 0; harmless re-read)
    const int tn = (t + 1) & (TILES - 1);
    const FragPOD* __restrict__ pn = pfrag + tn * 192 + lane;
    c0 = pn[0]; c1 = pn[64]; c2 = pn[128];
    const int nbn = tn * 16 + g4 * 4;
    nb0 = nbias[nbn + 0]; nb1 = nbias[nbn + 1];
    nb2 = nbias[nbn + 2]; nb3 = nbias[nbn + 3];

    const unsigned tb = (unsigned)(t * 16) + ib;
#pragma unroll
    for (int g = 0; g < 4; g++) {
      kvf4 acc;
      acc[0] = b0; acc[1] = b1; acc[2] = b2; acc[3] = b3;
      acc = __builtin_amdgcn_mfma_f32_16x16x32_f16(a0.v, bfr[g][0], acc, 0, 0, 0);
      acc = __builtin_amdgcn_mfma_f32_16x16x32_f16(a1.v, bfr[g][1], acc, 0, 0, 0);
      acc = __builtin_amdgcn_mfma_f32_16x16x32_f16(a2.v, bfr[g][2], acc, 0, 0, 0);
#pragma unroll
      for (int r = 0; r < 4; r++) {
        float kv = snorm[g] - acc[r];        // = 0.5||p-x||^2 >= 0 (up to rounding)
        kv = fmaxf(kv, 0.f);                 // keep uint order == float order
        const unsigned ku = (__float_as_uint(kv) & 0xFFFFF800u) | (tb + (unsigned)r);
        if      (g == 0) bub12(sk0, ku);
        else if (g == 1) bub12(sk1, ku);
        else if (g == 2) bub12(sk2, ku);
        else             bub12(sk3, ku);
      }
    }
  }

  // ---- per-g: fp32 rescore -> per-lane top-8 -> LDS merge -> gather/store ----
#pragma unroll 1
  for (int g = 0; g < 4; g++) {
    float xv[PS];
    const int pb = wid * 68 + g * 16 + l15;
#pragma unroll
    for (int c = 0; c < 3; c++)
#pragma unroll
      for (int dh = 0; dh < 5; dh++)
#pragma unroll
        for (int dw = 0; dw < 5; dw++)
          xv[(c * 5 + dh) * 5 + dw] = xt[pb + c * 544 + dh * 68 + dw];

    float rd[KNN];
    int ri[KNN];
#pragma unroll
    for (int j = 0; j < KNN; j++) { rd[j] = FLT_MAX; ri[j] = 0; }

#pragma unroll 1
    for (int j = 0; j < CK; j++) {
      const unsigned cj = (g == 0) ? sk0[j] : (g == 1) ? sk1[j] : (g == 2) ? sk2[j] : sk3[j];
      const int idx = (int)(cj & 0x7FFu);
      const float* __restrict__ pp = patches + idx * PS;
      float d0 = 0.f, d1 = 0.f, d2 = 0.f, d3 = 0.f;
#pragma unroll
      for (int u = 0; u < 18; u++) {
        d0 = fmaf(pp[4 * u + 0], xv[4 * u + 0], d0);
        d1 = fmaf(pp[4 * u + 1], xv[4 * u + 1], d1);
        d2 = fmaf(pp[4 * u + 2], xv[4 * u + 2], d2);
        d3 = fmaf(pp[4 * u + 3], xv[4 * u + 3], d3);
      }
      d0 = fmaf(pp[72], xv[72], d0);
      d1 = fmaf(pp[73], xv[73], d1);
      d2 = fmaf(pp[74], xv[74], d2);
      const float dot = (d0 + d1) + (d2 + d3);
      const float cd = -(nbias[idx] + dot);  // = 0.5||p||^2 - <p,x>, exact fp32
      ins8(cd, idx, rd, ri);
    }

    // dump per-lane top-8 to LDS; lane g4==0 merges the 4 disjoint subsets
#pragma unroll
    for (int s = 0; s < KNN; s++) {
      mg_d[wid][g4][l15][s] = rd[s];
      mg_i[wid][g4][l15][s] = ri[s];
    }
    __syncthreads();
    if (g4 == 0) {
#pragma unroll
      for (int q = 1; q < 4; q++)
#pragma unroll
        for (int s = 0; s < KNN; s++)
          ins8(mg_d[wid][q][l15][s], mg_i[wid][q][l15][s], rd, ri);
#pragma unroll
      for (int s = 0; s < KNN; s++) bc_i[wid][l15][s] = ri[s];
    }
    __syncthreads();

    // all 4 lanes read merged indices; lane handles dims [g4*32, g4*32+32)
    int mi[KNN];
#pragma unroll
    for (int s = 0; s < KNN; s++) mi[s] = bc_i[wid][l15][s] & 0x7FF;  // fault-defense
    const int obase = ((b * D_ + g4 * 32) * 64 + (h0 + wid)) * 64 + (g * 16 + l15);
#pragma unroll 1
    for (int dd = 0; dd < 32; dd += 4) {
      float s0 = 0.f, s1 = 0.f, s2 = 0.f, s3 = 0.f;
#pragma unroll
      for (int k = 0; k < KNN; k++) {
        const float4 v = *(const float4*)(values + mi[k] * D_ + g4 * 32 + dd);
        s0 += v.x; s1 += v.y; s2 += v.z; s3 += v.w;
      }
      out[obase + (dd + 0) * 4096] = s0 * 0.125f;
      out[obase + (dd + 1) * 4096] = s1 * 0.125f;
      out[obase + (dd + 2) * 4096] = s2 * 0.125f;
      out[obase + (dd + 3) * 4096] = s3 * 0.125f;
    }
  }
}

// ---------------------------------------------------------------------------
// Fallback: round-7 PASSING kernel verbatim (in-kernel A-build, no pfrag ws).
// ---------------------------------------------------------------------------
__global__ __launch_bounds__(256)
__attribute__((amdgpu_waves_per_eu(2, 4)))
void knn_fallback(const float* __restrict__ x, const float* __restrict__ patches,
                  const float* __restrict__ values, const float* __restrict__ nbias,
                  float* __restrict__ out) {
  __shared__ float xt[1633];
  __shared__ float mg_d[4][4][16][KNN];
  __shared__ int   mg_i[4][4][16][KNN];
  __shared__ int   bc_i[4][16][KNN];

  const int tid = threadIdx.x;
  const int bp = blockIdx.x * 256;
  const int b  = bp >> 12;
  const int h0 = (bp >> 6) & 63;

  for (int f = tid; f < 1632; f += 256) {
    const int c   = f / 544;
    const int rem = f - c * 544;
    const int j   = rem / 68;
    const int col = rem - j * 68;
    const int gr = h0 - 2 + j;
    const int gc = col - 2;
    float v = 0.f;
    if ((unsigned)gr < 64u && (unsigned)gc < 64u)
      v = x[((b * 3 + c) * 64 + gr) * 64 + gc];
    xt[f] = v;
  }
  if (tid == 0) xt[1632] = 0.f;
  __syncthreads();

  const int lane = tid & 63;
  const int wid  = tid >> 6;
  const int l15  = lane & 15;
  const int g4   = lane >> 4;

  kh8 bfr[4][3];
  float snorm[4];
#pragma unroll
  for (int g = 0; g < 4; g++) {
    const int pb = wid * 68 + g * 16 + l15;
#pragma unroll
    for (int s = 0; s < 3; s++) {
      union { _Float16 h[8]; kh8 v; } fr;
#pragma unroll
      for (int i = 0; i < 8; i++) {
        const int k  = s * 32 + g4 * 8 + i;
        const int c  = k / 25;
        const int r2 = k - c * 25;
        const int addr = (k < PS) ? (pb + c * 544 + (r2 / 5) * 68 + (r2 % 5)) : 1632;
        fr.h[i] = (_Float16)xt[addr];
      }
      bfr[g][s] = fr.v;
    }
    float sq = 0.f;
#pragma unroll
    for (int c = 0; c < 3; c++)
#pragma unroll
      for (int dh = 0; dh < 5; dh++)
#pragma unroll
        for (int dw = 0; dw < 5; dw++) {
          const _Float16 hv = (_Float16)xt[pb + c * 544 + dh * 68 + dw];
          const float vr = (float)hv;
          sq = fmaf(vr, vr, sq);
        }
    snorm[g] = 0.5f * sq;
  }

  unsigned sk0[CK], sk1[CK], sk2[CK], sk3[CK];
#pragma unroll
  for (int j = 0; j < CK; j++) sk0[j] = sk1[j] = sk2[j] = sk3[j] = 0xFFFFFFFFu;

#pragma unroll 1
  for (int t = 0; t < TILES; t++) {
    const float* __restrict__ pr = patches + (t * 16 + l15) * PS + g4 * 8;
    union { _Float16 h[8]; kh8 v; } af[3];
#pragma unroll
    for (int s = 0; s < 3; s++)
#pragma unroll
      for (int i = 0; i < 8; i++) {
        const int k = s * 32 + g4 * 8 + i;
        const float e = (k < PS) ? pr[s * 32 + i] : 0.f;
        af[s].h[i] = (_Float16)e;
      }

    const int nbb = t * 16 + g4 * 4;
    const float nb0 = nbias[nbb + 0];
    const float nb1 = nbias[nbb + 1];
    const float nb2 = nbias[nbb + 2];
    const float nb3 = nbias[nbb + 3];
    const unsigned tb = (unsigned)nbb;
#pragma unroll
    for (int g = 0; g < 4; g++) {
      kvf4 acc;
      acc[0] = nb0; acc[1] = nb1; acc[2] = nb2; acc[3] = nb3;
      acc = __builtin_amdgcn_mfma_f32_16x16x32_f16(af[0].v, bfr[g][0], acc, 0, 0, 0);
      acc = __builtin_amdgcn_mfma_f32_16x16x32_f16(af[1].v, bfr[g][1], acc, 0, 0, 0);
      acc = __builtin_amdgcn_mfma_f32_16x16x32_f16(af[2].v, bfr[g][2], acc, 0, 0, 0);
#pragma unroll
      for (int r = 0; r < 4; r++) {
        float kv = snorm[g] - acc[r];
        kv = fmaxf(kv, 0.f);
        const unsigned ku = (__float_as_uint(kv) & 0xFFFFF800u) | (tb + (unsigned)r);
        if      (g == 0) bub12(sk0, ku);
        else if (g == 1) bub12(sk1, ku);
        else if (g == 2) bub12(sk2, ku);
        else             bub12(sk3, ku);
      }
    }
  }

#pragma unroll 1
  for (int g = 0; g < 4; g++) {
    float xv[PS];
    const int pb = wid * 68 + g * 16 + l15;
#pragma unroll
    for (int c = 0; c < 3; c++)
#pragma unroll
      for (int dh = 0; dh < 5; dh++)
#pragma unroll
        for (int dw = 0; dw < 5; dw++)
          xv[(c * 5 + dh) * 5 + dw] = xt[pb + c * 544 + dh * 68 + dw];

    float rd[KNN];
    int ri[KNN];
#pragma unroll
    for (int j = 0; j < KNN; j++) { rd[j] = FLT_MAX; ri[j] = 0; }

#pragma unroll 1
    for (int j = 0; j < CK; j++) {
      const unsigned cj = (g == 0) ? sk0[j] : (g == 1) ? sk1[j] : (g == 2) ? sk2[j] : sk3[j];
      const int idx = (int)(cj & 0x7FFu);
      const float* __restrict__ pp = patches + idx * PS;
      float d0 = 0.f, d1 = 0.f, d2 = 0.f, d3 = 0.f;
#pragma unroll
      for (int u = 0; u < 18; u++) {
        d0 = fmaf(pp[4 * u + 0], xv[4 * u + 0], d0);
        d1 = fmaf(pp[4 * u + 1], xv[4 * u + 1], d1);
        d2 = fmaf(pp[4 * u + 2], xv[4 * u + 2], d2);
        d3 = fmaf(pp[4 * u + 3], xv[4 * u + 3], d3);
      }
      d0 = fmaf(pp[72], xv[72], d0);
      d1 = fmaf(pp[73], xv[73], d1);
      d2 = fmaf(pp[74], xv[74], d2);
      const float dot = (d0 + d1) + (d2 + d3);
      const float cd = -(nbias[idx] + dot);
      ins8(cd, idx, rd, ri);
    }

#pragma unroll
    for (int s = 0; s < KNN; s++) {
      mg_d[wid][g4][l15][s] = rd[s];
      mg_i[wid][g4][l15][s] = ri[s];
    }
    __syncthreads();
    if (g4 == 0) {
#pragma unroll
      for (int q = 1; q < 4; q++)
#pragma unroll
        for (int s = 0; s < KNN; s++)
          ins8(mg_d[wid][q][l15][s], mg_i[wid][q][l15][s], rd, ri);
#pragma unroll
      for (int s = 0; s < KNN; s++) bc_i[wid][l15][s] = ri[s];
    }
    __syncthreads();

    int mi[KNN];
#pragma unroll
    for (int s = 0; s < KNN; s++) mi[s] = bc_i[wid][l15][s] & 0x7FF;
    const int obase = ((b * D_ + g4 * 32) * 64 + (h0 + wid)) * 64 + (g * 16 + l15);
#pragma unroll 1
    for (int dd = 0; dd < 32; dd += 4) {
      float s0 = 0.f, s1 = 0.f, s2 = 0.f, s3 = 0.f;
#pragma unroll
      for (int k = 0; k < KNN; k++) {
        const float4 v = *(const float4*)(values + mi[k] * D_ + g4 * 32 + dd);
        s0 += v.x; s1 += v.y; s2 += v.z; s3 += v.w;
      }
      out[obase + (dd + 0) * 4096] = s0 * 0.125f;
      out[obase + (dd + 1) * 4096] = s1 * 0.125f;
      out[obase + (dd + 2) * 4096] = s2 * 0.125f;
      out[obase + (dd + 3) * 4096] = s3 * 0.125f;
    }
  }
}

// ---------------------------------------------------------------------------
extern "C" void kernel_launch(void* const* d_in, const int* in_sizes, int n_in,
                              void* d_out, int out_size, void* d_ws, size_t ws_size,
                              hipStream_t stream) {
  const float* x = (const float*)d_in[0];
  const float* patches = (const float*)d_in[1];
  const float* values = (const float*)d_in[2];
  float* out = (float*)d_out;

  const size_t PFRAG_B = (size_t)TILES * 3 * 64 * 16;  // 393216 B
  const size_t BIAS_B  = (size_t)N_ * 4;               // 8192 B

  if (ws_size >= PFRAG_B + BIAS_B) {
    FragPOD* pfrag = (FragPOD*)d_ws;
    float* nbias   = (float*)((char*)d_ws + PFRAG_B);
    hipLaunchKernelGGL(bias_kernel, dim3(N_ / 256), dim3(256), 0, stream, patches, nbias);
    hipLaunchKernelGGL(pfrag_kernel, dim3(TILES), dim3(192), 0, stream, patches, pfrag);
    hipLaunchKernelGGL(knn_kernel, dim3((B_ * H_ * W_) / 256), dim3(256), 0, stream,
                       x, patches, values, nbias, pfrag, out);
  } else {
    float* nbias = (float*)d_ws;  // 8 KB scratch
    hipLaunchKernelGGL(bias_kernel, dim3(N_ / 256), dim3(256), 0, stream, patches, nbias);
    hipLaunchKernelGGL(knn_fallback, dim3((B_ * H_ * W_) / 256), dim3(256), 0, stream,
                       x, patches, values, nbias, out);
  }
}

// Round 9
// 587.945 us; speedup vs baseline: 2.0676x; 1.0951x over previous
//
#include <hip/hip_runtime.h>
#include <float.h>

#define B_  32
#define C_  3
#define H_  64
#define W_  64
#define N_  2048
#define D_  128
#define KNN 8
#define PS  75       // 3*5*5
#define TILES 128    // N_/16 patch tiles
#define CK  12       // coarse per-lane top-k (margin over 8 for f16 ranking noise)

typedef __attribute__((ext_vector_type(8))) _Float16 kh8;   // register-only (MFMA A/B)
typedef __attribute__((ext_vector_type(4))) float kvf4;     // register-only (MFMA C/D)

struct FragPOD { unsigned a, b, c, d; };   // 16B POD for global frag store/load

// x-window element k (0..74) -> offset in the [3][5][68] row tile
__device__ __forceinline__ constexpr int xoff(int k) {
  return (k / 25) * 340 + ((k % 25) / 5) * 68 + ((k % 25) % 5);
}

// ---------------------------------------------------------------------------
// Kernel 1: nbias[n] = -0.5 * ||patches[n]||^2
// ---------------------------------------------------------------------------
__global__ __launch_bounds__(256) void bias_kernel(const float* __restrict__ patches,
                                                   float* __restrict__ nbias) {
  int n = blockIdx.x * 256 + threadIdx.x;
  if (n < N_) {
    const float* __restrict__ p = patches + n * PS;
    float s = 0.f;
#pragma unroll
    for (int j = 0; j < PS; j++) s += p[j] * p[j];
    nbias[n] = -0.5f * s;
  }
}

// ---------------------------------------------------------------------------
// Kernel 1b: A-fragments (f16, MFMA layout) precomputed once. Tile t, K-step s,
// lane l: elem i <-> (m = t*16+(l&15), k = s*32+(l>>4)*8+i), masked k<75.
// ---------------------------------------------------------------------------
__global__ __launch_bounds__(192) void pfrag_kernel(const float* __restrict__ patches,
                                                    FragPOD* __restrict__ pfrag) {
  const int t = blockIdx.x;
  const int s = threadIdx.x >> 6;
  const int l = threadIdx.x & 63;
  const int m = t * 16 + (l & 15);
  const int g4 = l >> 4;
  union { _Float16 h[8]; FragPOD f; } fr;
#pragma unroll
  for (int i = 0; i < 8; i++) {
    const int k = s * 32 + g4 * 8 + i;
    const float v = (k < PS) ? patches[m * PS + k] : 0.f;
    fr.h[i] = (_Float16)v;
  }
  pfrag[(t * 3 + s) * 64 + l] = fr.f;
}

// branchless ascending bubble insert into a CK-deep sorted register list
__device__ __forceinline__ void bub12(unsigned (&s)[CK], unsigned c) {
#pragma unroll
  for (int j = 0; j < CK; j++) {
    const unsigned lo = s[j] < c ? s[j] : c;
    const unsigned hi = s[j] < c ? c : s[j];
    s[j] = lo;
    c = hi;
  }
}

// lexicographic (d, idx) ascending 8-deep bubble insert
__device__ __forceinline__ void ins8(float cd, int ci, float (&rd)[KNN], int (&ri)[KNN]) {
#pragma unroll
  for (int q = 0; q < KNN; q++) {
    const bool sw = (cd < rd[q]) || (cd == rd[q] && ci < ri[q]);
    const float nd = sw ? rd[q] : cd;
    const int   ni = sw ? ri[q] : ci;
    rd[q] = sw ? cd : rd[q];
    ri[q] = sw ? ci : ri[q];
    cd = nd;
    ci = ni;
  }
}

// ---------------------------------------------------------------------------
// Kernel 2 (restructured from the R8 passing kernel): block = 4 waves = ONE
// image row of 64 pixels; each wave owns ONE 16-pixel group (R8's wave owned
// four). Grid 2048 blocks -> 8 blocks/CU (R8: 2, grid-limited 21% occupancy).
// Per-lane t-loop state drops to ~60 VGPRs (bfr 12 + sk 12 + prefetch 12) and
// the rescore reads x straight from LDS (broadcast, conflict-free) instead of
// a 75-reg xv[] -> no scratch spills (R8: ~120 MB spill traffic).
// ---------------------------------------------------------------------------
__global__ __launch_bounds__(256)
__attribute__((amdgpu_waves_per_eu(4, 8)))
void knn_kernel(const float* __restrict__ x, const float* __restrict__ patches,
                const float* __restrict__ values, const float* __restrict__ nbias,
                const FragPOD* __restrict__ pfrag, float* __restrict__ out) {
  __shared__ float xt[1024];                 // [3][5][68] zero-padded row tile + zero cell
  __shared__ float mg_d[4][4][16][KNN];      // [wave][g4][l15][slot] merge staging
  __shared__ int   mg_i[4][4][16][KNN];      // (merged idx re-broadcast via [wave][0])

  const int tid = threadIdx.x;
  const int blk = blockIdx.x;                // 2048 = 32 images x 64 rows
  const int b = blk >> 6;
  const int h = blk & 63;

  for (int f = tid; f < 1020; f += 256) {
    const int c   = f / 340;
    const int rem = f - c * 340;
    const int dh  = rem / 68;
    const int col = rem - dh * 68;
    const int gr = h - 2 + dh;
    const int gc = col - 2;
    float v = 0.f;
    if ((unsigned)gr < 64u && (unsigned)gc < 64u)
      v = x[((b * 3 + c) * 64 + gr) * 64 + gc];
    xt[f] = v;
  }
  if (tid < 4) xt[1020 + tid] = 0.f;
  __syncthreads();

  const int lane = tid & 63;
  const int wq   = tid >> 6;                 // wave id: pixel cols [wq*16, wq*16+16)
  const int l15  = lane & 15;
  const int g4   = lane >> 4;
  const int pcol = wq * 16 + l15;            // this lane's pixel column

  // ---- B fragments (f16 x-window of pixel pcol) + 0.5||x~||^2 ----
  kh8 bfr[3];
#pragma unroll
  for (int s = 0; s < 3; s++) {
    union { _Float16 h[8]; kh8 v; } fr;
#pragma unroll
    for (int i = 0; i < 8; i++) {
      const int k = s * 32 + g4 * 8 + i;
      const int addr = (k < PS) ? (xoff(k) + pcol) : 1020;
      fr.h[i] = (_Float16)xt[addr];
    }
    bfr[s] = fr.v;
  }
  float sq = 0.f;
#pragma unroll
  for (int k = 0; k < PS; k++) {
    const _Float16 hv = (_Float16)xt[xoff(k) + pcol];
    const float vr = (float)hv;
    sq = fmaf(vr, vr, sq);
  }
  const float snorm = 0.5f * sq;

  // ---- coarse top-CK per lane (patch rows m: m mod 16 in [g4*4, g4*4+4)) ----
  unsigned sk[CK];
#pragma unroll
  for (int j = 0; j < CK; j++) sk[j] = 0xFFFFFFFFu;

  FragPOD c0 = pfrag[lane];
  FragPOD c1 = pfrag[64 + lane];
  FragPOD c2 = pfrag[128 + lane];
  float nb0 = nbias[g4 * 4 + 0];
  float nb1 = nbias[g4 * 4 + 1];
  float nb2 = nbias[g4 * 4 + 2];
  float nb3 = nbias[g4 * 4 + 3];

#pragma unroll 1
  for (int t = 0; t < TILES; t++) {
    union { FragPOD f; kh8 v; } a0, a1, a2;
    a0.f = c0; a1.f = c1; a2.f = c2;
    const float b0 = nb0, b1 = nb1, b2 = nb2, b3 = nb3;

    const int tn = (t + 1) & (TILES - 1);    // t=127 wraps; harmless re-read
    const FragPOD* __restrict__ pn = pfrag + tn * 192 + lane;
    c0 = pn[0]; c1 = pn[64]; c2 = pn[128];
    const int nbn = tn * 16 + g4 * 4;
    nb0 = nbias[nbn + 0]; nb1 = nbias[nbn + 1];
    nb2 = nbias[nbn + 2]; nb3 = nbias[nbn + 3];

    kvf4 acc;
    acc[0] = b0; acc[1] = b1; acc[2] = b2; acc[3] = b3;
    acc = __builtin_amdgcn_mfma_f32_16x16x32_f16(a0.v, bfr[0], acc, 0, 0, 0);
    acc = __builtin_amdgcn_mfma_f32_16x16x32_f16(a1.v, bfr[1], acc, 0, 0, 0);
    acc = __builtin_amdgcn_mfma_f32_16x16x32_f16(a2.v, bfr[2], acc, 0, 0, 0);

    const unsigned tb = (unsigned)(t * 16 + g4 * 4);
#pragma unroll
    for (int r = 0; r < 4; r++) {
      float kv = snorm - acc[r];             // = 0.5||p-x||^2 >= 0 (up to rounding)
      kv = fmaxf(kv, 0.f);                   // keep uint order == float order
      const unsigned ku = (__float_as_uint(kv) & 0xFFFFF800u) | (tb + (unsigned)r);
      bub12(sk, ku);
    }
  }

  // ---- exact fp32 rescore (x read from LDS: broadcast, no xv[] registers) ----
  float rd[KNN];
  int ri[KNN];
#pragma unroll
  for (int j = 0; j < KNN; j++) { rd[j] = FLT_MAX; ri[j] = 0; }

#pragma unroll 1
  for (int j = 0; j < CK; j++) {
    const int idx = (int)(sk[j] & 0x7FFu);
    const float* __restrict__ pp = patches + idx * PS;
    float d0 = 0.f, d1 = 0.f, d2 = 0.f, d3 = 0.f;
#pragma unroll
    for (int u = 0; u < 18; u++) {
      const float4 p4 = *(const float4*)(pp + 4 * u);
      d0 = fmaf(p4.x, xt[xoff(4 * u + 0) + pcol], d0);
      d1 = fmaf(p4.y, xt[xoff(4 * u + 1) + pcol], d1);
      d2 = fmaf(p4.z, xt[xoff(4 * u + 2) + pcol], d2);
      d3 = fmaf(p4.w, xt[xoff(4 * u + 3) + pcol], d3);
    }
    d0 = fmaf(pp[72], xt[xoff(72) + pcol], d0);
    d1 = fmaf(pp[73], xt[xoff(73) + pcol], d1);
    d2 = fmaf(pp[74], xt[xoff(74) + pcol], d2);
    const float dot = (d0 + d1) + (d2 + d3);
    const float cd = -(nbias[idx] + dot);    // = 0.5||p||^2 - <p,x>, exact fp32
    ins8(cd, idx, rd, ri);
  }

  // ---- merge the 4 disjoint per-lane sets (same l15, g4 = 0..3) via LDS ----
#pragma unroll
  for (int s = 0; s < KNN; s++) {
    mg_d[wq][g4][l15][s] = rd[s];
    mg_i[wq][g4][l15][s] = ri[s];
  }
  __syncthreads();
  if (g4 == 0) {
#pragma unroll
    for (int q = 1; q < 4; q++)
#pragma unroll
      for (int s = 0; s < KNN; s++)
        ins8(mg_d[wq][q][l15][s], mg_i[wq][q][l15][s], rd, ri);
#pragma unroll
    for (int s = 0; s < KNN; s++) mg_i[wq][0][l15][s] = ri[s];
  }
  __syncthreads();

  // ---- gather/mean/store: lane handles dims [g4*32, g4*32+32) of pixel pcol ----
  int mi[KNN];
#pragma unroll
  for (int s = 0; s < KNN; s++) mi[s] = mg_i[wq][0][l15][s] & 0x7FF;  // fault-defense
  const int obase = ((b * D_ + g4 * 32) * 64 + h) * 64 + pcol;
#pragma unroll 1
  for (int dd = 0; dd < 32; dd += 4) {
    float s0 = 0.f, s1 = 0.f, s2 = 0.f, s3 = 0.f;
#pragma unroll
    for (int k = 0; k < KNN; k++) {
      const float4 v = *(const float4*)(values + mi[k] * D_ + g4 * 32 + dd);
      s0 += v.x; s1 += v.y; s2 += v.z; s3 += v.w;
    }
    out[obase + (dd + 0) * 4096] = s0 * 0.125f;
    out[obase + (dd + 1) * 4096] = s1 * 0.125f;
    out[obase + (dd + 2) * 4096] = s2 * 0.125f;
    out[obase + (dd + 3) * 4096] = s3 * 0.125f;
  }
}

// ---------------------------------------------------------------------------
// Fallback: round-7 PASSING kernel verbatim (in-kernel A-build, bias-only ws).
// ---------------------------------------------------------------------------
__global__ __launch_bounds__(256)
__attribute__((amdgpu_waves_per_eu(2, 4)))
void knn_fallback(const float* __restrict__ x, const float* __restrict__ patches,
                  const float* __restrict__ values, const float* __restrict__ nbias,
                  float* __restrict__ out) {
  __shared__ float xtf[1633];
  __shared__ float mg_d[4][4][16][KNN];
  __shared__ int   mg_i[4][4][16][KNN];
  __shared__ int   bc_i[4][16][KNN];

  const int tid = threadIdx.x;
  const int bp = blockIdx.x * 256;
  const int b  = bp >> 12;
  const int h0 = (bp >> 6) & 63;

  for (int f = tid; f < 1632; f += 256) {
    const int c   = f / 544;
    const int rem = f - c * 544;
    const int j   = rem / 68;
    const int col = rem - j * 68;
    const int gr = h0 - 2 + j;
    const int gc = col - 2;
    float v = 0.f;
    if ((unsigned)gr < 64u && (unsigned)gc < 64u)
      v = x[((b * 3 + c) * 64 + gr) * 64 + gc];
    xtf[f] = v;
  }
  if (tid == 0) xtf[1632] = 0.f;
  __syncthreads();

  const int lane = tid & 63;
  const int wid  = tid >> 6;
  const int l15  = lane & 15;
  const int g4   = lane >> 4;

  kh8 bfr[4][3];
  float snorm[4];
#pragma unroll
  for (int g = 0; g < 4; g++) {
    const int pb = wid * 68 + g * 16 + l15;
#pragma unroll
    for (int s = 0; s < 3; s++) {
      union { _Float16 h[8]; kh8 v; } fr;
#pragma unroll
      for (int i = 0; i < 8; i++) {
        const int k  = s * 32 + g4 * 8 + i;
        const int c  = k / 25;
        const int r2 = k - c * 25;
        const int addr = (k < PS) ? (pb + c * 544 + (r2 / 5) * 68 + (r2 % 5)) : 1632;
        fr.h[i] = (_Float16)xtf[addr];
      }
      bfr[g][s] = fr.v;
    }
    float sq = 0.f;
#pragma unroll
    for (int c = 0; c < 3; c++)
#pragma unroll
      for (int dh = 0; dh < 5; dh++)
#pragma unroll
        for (int dw = 0; dw < 5; dw++) {
          const _Float16 hv = (_Float16)xtf[pb + c * 544 + dh * 68 + dw];
          const float vr = (float)hv;
          sq = fmaf(vr, vr, sq);
        }
    snorm[g] = 0.5f * sq;
  }

  unsigned sk0[CK], sk1[CK], sk2[CK], sk3[CK];
#pragma unroll
  for (int j = 0; j < CK; j++) sk0[j] = sk1[j] = sk2[j] = sk3[j] = 0xFFFFFFFFu;

#pragma unroll 1
  for (int t = 0; t < TILES; t++) {
    const float* __restrict__ pr = patches + (t * 16 + l15) * PS + g4 * 8;
    union { _Float16 h[8]; kh8 v; } af[3];
#pragma unroll
    for (int s = 0; s < 3; s++)
#pragma unroll
      for (int i = 0; i < 8; i++) {
        const int k = s * 32 + g4 * 8 + i;
        const float e = (k < PS) ? pr[s * 32 + i] : 0.f;
        af[s].h[i] = (_Float16)e;
      }

    const int nbb = t * 16 + g4 * 4;
    const float nb0 = nbias[nbb + 0];
    const float nb1 = nbias[nbb + 1];
    const float nb2 = nbias[nbb + 2];
    const float nb3 = nbias[nbb + 3];
    const unsigned tb = (unsigned)nbb;
#pragma unroll
    for (int g = 0; g < 4; g++) {
      kvf4 acc;
      acc[0] = nb0; acc[1] = nb1; acc[2] = nb2; acc[3] = nb3;
      acc = __builtin_amdgcn_mfma_f32_16x16x32_f16(af[0].v, bfr[g][0], acc, 0, 0, 0);
      acc = __builtin_amdgcn_mfma_f32_16x16x32_f16(af[1].v, bfr[g][1], acc, 0, 0, 0);
      acc = __builtin_amdgcn_mfma_f32_16x16x32_f16(af[2].v, bfr[g][2], acc, 0, 0, 0);
#pragma unroll
      for (int r = 0; r < 4; r++) {
        float kv = snorm[g] - acc[r];
        kv = fmaxf(kv, 0.f);
        const unsigned ku = (__float_as_uint(kv) & 0xFFFFF800u) | (tb + (unsigned)r);
        if      (g == 0) bub12(sk0, ku);
        else if (g == 1) bub12(sk1, ku);
        else if (g == 2) bub12(sk2, ku);
        else             bub12(sk3, ku);
      }
    }
  }

#pragma unroll 1
  for (int g = 0; g < 4; g++) {
    float xv[PS];
    const int pb = wid * 68 + g * 16 + l15;
#pragma unroll
    for (int c = 0; c < 3; c++)
#pragma unroll
      for (int dh = 0; dh < 5; dh++)
#pragma unroll
        for (int dw = 0; dw < 5; dw++)
          xv[(c * 5 + dh) * 5 + dw] = xtf[pb + c * 544 + dh * 68 + dw];

    float rd[KNN];
    int ri[KNN];
#pragma unroll
    for (int j = 0; j < KNN; j++) { rd[j] = FLT_MAX; ri[j] = 0; }

#pragma unroll 1
    for (int j = 0; j < CK; j++) {
      const unsigned cj = (g == 0) ? sk0[j] : (g == 1) ? sk1[j] : (g == 2) ? sk2[j] : sk3[j];
      const int idx = (int)(cj & 0x7FFu);
      const float* __restrict__ pp = patches + idx * PS;
      float d0 = 0.f, d1 = 0.f, d2 = 0.f, d3 = 0.f;
#pragma unroll
      for (int u = 0; u < 18; u++) {
        d0 = fmaf(pp[4 * u + 0], xv[4 * u + 0], d0);
        d1 = fmaf(pp[4 * u + 1], xv[4 * u + 1], d1);
        d2 = fmaf(pp[4 * u + 2], xv[4 * u + 2], d2);
        d3 = fmaf(pp[4 * u + 3], xv[4 * u + 3], d3);
      }
      d0 = fmaf(pp[72], xv[72], d0);
      d1 = fmaf(pp[73], xv[73], d1);
      d2 = fmaf(pp[74], xv[74], d2);
      const float dot = (d0 + d1) + (d2 + d3);
      const float cd = -(nbias[idx] + dot);
      ins8(cd, idx, rd, ri);
    }

#pragma unroll
    for (int s = 0; s < KNN; s++) {
      mg_d[wid][g4][l15][s] = rd[s];
      mg_i[wid][g4][l15][s] = ri[s];
    }
    __syncthreads();
    if (g4 == 0) {
#pragma unroll
      for (int q = 1; q < 4; q++)
#pragma unroll
        for (int s = 0; s < KNN; s++)
          ins8(mg_d[wid][q][l15][s], mg_i[wid][q][l15][s], rd, ri);
#pragma unroll
      for (int s = 0; s < KNN; s++) bc_i[wid][l15][s] = ri[s];
    }
    __syncthreads();

    int mi[KNN];
#pragma unroll
    for (int s = 0; s < KNN; s++) mi[s] = bc_i[wid][l15][s] & 0x7FF;
    const int obase = ((b * D_ + g4 * 32) * 64 + (h0 + wid)) * 64 + (g * 16 + l15);
#pragma unroll 1
    for (int dd = 0; dd < 32; dd += 4) {
      float s0 = 0.f, s1 = 0.f, s2 = 0.f, s3 = 0.f;
#pragma unroll
      for (int k = 0; k < KNN; k++) {
        const float4 v = *(const float4*)(values + mi[k] * D_ + g4 * 32 + dd);
        s0 += v.x; s1 += v.y; s2 += v.z; s3 += v.w;
      }
      out[obase + (dd + 0) * 4096] = s0 * 0.125f;
      out[obase + (dd + 1) * 4096] = s1 * 0.125f;
      out[obase + (dd + 2) * 4096] = s2 * 0.125f;
      out[obase + (dd + 3) * 4096] = s3 * 0.125f;
    }
  }
}

// ---------------------------------------------------------------------------
extern "C" void kernel_launch(void* const* d_in, const int* in_sizes, int n_in,
                              void* d_out, int out_size, void* d_ws, size_t ws_size,
                              hipStream_t stream) {
  const float* x = (const float*)d_in[0];
  const float* patches = (const float*)d_in[1];
  const float* values = (const float*)d_in[2];
  float* out = (float*)d_out;

  const size_t PFRAG_B = (size_t)TILES * 3 * 64 * 16;  // 393216 B
  const size_t BIAS_B  = (size_t)N_ * 4;               // 8192 B

  if (ws_size >= PFRAG_B + BIAS_B) {
    FragPOD* pfrag = (FragPOD*)d_ws;
    float* nbias   = (float*)((char*)d_ws + PFRAG_B);
    hipLaunchKernelGGL(bias_kernel, dim3(N_ / 256), dim3(256), 0, stream, patches, nbias);
    hipLaunchKernelGGL(pfrag_kernel, dim3(TILES), dim3(192), 0, stream, patches, pfrag);
    hipLaunchKernelGGL(knn_kernel, dim3(B_ * H_), dim3(256), 0, stream,
                       x, patches, values, nbias, pfrag, out);
  } else {
    float* nbias = (float*)d_ws;  // 8 KB scratch
    hipLaunchKernelGGL(bias_kernel, dim3(N_ / 256), dim3(256), 0, stream, patches, nbias);
    hipLaunchKernelGGL(knn_fallback, dim3((B_ * H_ * W_) / 128), dim3(256), 0, stream,
                       x, patches, values, nbias, out);
  }
}